// Round 5
// baseline (168.738 us; speedup 1.0000x reference)
//
#include <hip/hip_runtime.h>

#define CMAX    1000
#define CPAD    64            // cursor padding (ints) = 256 B, spreads L2 channels
#define FIXS    1048576.0f    // 2^20 fixed-point scale
#define INVFIXS (1.0f / 1048576.0f)

// ---------------------------------------------------------------------------
// Pass A: label histogram (LDS-privatized, trivial) -> tot[c]
// ---------------------------------------------------------------------------
__global__ __launch_bounds__(256) void hist_kernel(
    const int* __restrict__ l, int* __restrict__ tot, int B)
{
    __shared__ int h[CMAX];
    for (int i = threadIdx.x; i < CMAX; i += 256) h[i] = 0;
    __syncthreads();
    const int per  = (B + gridDim.x - 1) / gridDim.x;
    const int base = blockIdx.x * per;
    const int end  = min(B, base + per);
    for (int i = base + threadIdx.x; i < end; i += 256)
        atomicAdd(&h[l[i]], 1);
    __syncthreads();
    for (int i = threadIdx.x; i < CMAX; i += 256) {
        const int v = h[i];
        if (v) atomicAdd(&tot[i], v);
    }
}

// ---------------------------------------------------------------------------
// Pass B: exclusive scan of tot -> cursor[c*CPAD]; also cnt_i[c] = tot[c]
// ---------------------------------------------------------------------------
__global__ __launch_bounds__(1024) void scan_kernel(
    const int* __restrict__ tot, int* __restrict__ cursor,
    int* __restrict__ cnt_i, int C)
{
    __shared__ int s[1024];
    const int t = threadIdx.x;
    const int v = (t < C) ? tot[t] : 0;
    s[t] = v;
    if (t < C) cnt_i[t] = v;
    for (int off = 1; off < 1024; off <<= 1) {
        __syncthreads();
        const int u = (t >= off) ? s[t - off] : 0;
        __syncthreads();
        s[t] += u;
    }
    __syncthreads();
    if (t < C) cursor[t * CPAD] = s[t] - v;   // exclusive prefix
}

// ---------------------------------------------------------------------------
// Pass C: build class-sorted permutation via padded global atomic ranks.
// Order within a class is nondeterministic, but downstream int accumulation
// is order-independent -> output is bit-deterministic.
// ---------------------------------------------------------------------------
__global__ __launch_bounds__(256) void build_kernel(
    const int* __restrict__ l, int* __restrict__ cursor,
    int* __restrict__ perm, int* __restrict__ lsorted, int B)
{
    const int per  = (B + gridDim.x - 1) / gridDim.x;
    const int base = blockIdx.x * per;
    const int end  = min(B, base + per);
    for (int i = base + threadIdx.x; i < end; i += 256) {
        const int c   = l[i];
        const int pos = atomicAdd(&cursor[c * CPAD], 1);
        perm[pos]    = i;
        lsorted[pos] = c;
    }
}

// ---------------------------------------------------------------------------
// Pass D: segment-sum over sorted order. One wave per row-stream:
// each row is ONE contiguous 1KB wave load (lane k holds dims 4k..4k+3).
// Register fixed-point accumulation; flush once per class-run via native
// int global atomics. Zero LDS usage.
// ---------------------------------------------------------------------------
#define SPAN 64
__global__ __launch_bounds__(256) void segsum_kernel(
    const float* __restrict__ x, const int* __restrict__ perm,
    const int* __restrict__ lsorted, int* __restrict__ sums_i, int B, int D)
{
    const int lane = threadIdx.x & 63;
    const int wid  = (int)((blockIdx.x * blockDim.x + threadIdx.x) >> 6);
    const int p0 = wid * SPAN;
    if (p0 >= B) return;
    const int p1 = min(B, p0 + SPAN);
    const int DV = D >> 2;
    const float4* __restrict__ x4 = (const float4*)x;

    int cur = lsorted[p0];
    int ax = 0, ay = 0, az = 0, aw = 0;

    // 1-deep prefetch of the next row's index/label/data
    int    c_n   = cur;
    int    idx_n = perm[p0];
    float4 v_n   = x4[(size_t)idx_n * DV + lane];

    for (int p = p0; p < p1; ++p) {
        const float4 v = v_n;
        const int    c = c_n;
        if (p + 1 < p1) {
            const int idx2 = perm[p + 1];
            c_n = lsorted[p + 1];
            v_n = x4[(size_t)idx2 * DV + lane];
        }
        if (c != cur) {                       // wave-uniform, rare
            int* dst = sums_i + (size_t)cur * D + (lane << 2);
            atomicAdd(dst + 0, ax);
            atomicAdd(dst + 1, ay);
            atomicAdd(dst + 2, az);
            atomicAdd(dst + 3, aw);
            ax = ay = az = aw = 0;
            cur = c;
        }
        ax += __float2int_rn(v.x * FIXS);
        ay += __float2int_rn(v.y * FIXS);
        az += __float2int_rn(v.z * FIXS);
        aw += __float2int_rn(v.w * FIXS);
    }
    int* dst = sums_i + (size_t)cur * D + (lane << 2);
    atomicAdd(dst + 0, ax);
    atomicAdd(dst + 1, ay);
    atomicAdd(dst + 2, az);
    atomicAdd(dst + 3, aw);
}

// ---------------------------------------------------------------------------
// block-wide sum over 256 threads (4 waves); result broadcast to all threads
// ---------------------------------------------------------------------------
__device__ __forceinline__ float block_reduce_sum_256(float v, float* sbuf) {
    #pragma unroll
    for (int o = 32; o > 0; o >>= 1) v += __shfl_down(v, o, 64);
    __syncthreads();                 // protect sbuf across repeated calls
    if ((threadIdx.x & 63) == 0) sbuf[threadIdx.x >> 6] = v;
    __syncthreads();
    return sbuf[0] + sbuf[1] + sbuf[2] + sbuf[3];
}

// ---------------------------------------------------------------------------
// Kernel: per-class momentum update + L2 renorm + squared distance.
// One block (256 threads == D) per class.
// ---------------------------------------------------------------------------
__global__ __launch_bounds__(256) void update_kernel(
    const int* __restrict__ sums_i, const int* __restrict__ cnt_i,
    const float* __restrict__ cimg, const float* __restrict__ cskt,
    float* __restrict__ sq_out, float* __restrict__ pres_out, int C, int D)
{
    __shared__ float sbuf[4];
    __shared__ float cshare;
    const int c = blockIdx.x;
    const int t = threadIdx.x;

    const float ssum = (float)sums_i[(size_t)c * D + t] * INVFIXS;
    if (t == 0) cshare = (float)cnt_i[c];
    __syncthreads();
    const float cnt = cshare;

    const bool present = cnt > 0.5f;
    const size_t idx = (size_t)c * D + t;
    const float ci = cimg[idx];
    const float cs = cskt[idx];
    const float mean = ssum / fmaxf(cnt, 1.f);
    const float upd = ci * 0.9f + mean * 0.1f;
    const float n2 = block_reduce_sum_256(upd * upd, sbuf);
    const float inv = 1.0f / sqrtf(n2);
    const float newv = present ? upd * inv : ci;
    const float df = newv - cs;
    const float sq = block_reduce_sum_256(df * df, sbuf);
    if (t == 0) {
        sq_out[c]   = present ? sq : 0.f;
        pres_out[c] = present ? 1.f : 0.f;
    }
}

// ---------------------------------------------------------------------------
// Final reduction over classes -> scalar loss
// ---------------------------------------------------------------------------
__global__ __launch_bounds__(256) void finalize_kernel(
    const float* __restrict__ sq, const float* __restrict__ pres,
    float* __restrict__ out, int C)
{
    __shared__ float sbuf[4];
    float ls = 0.f, np = 0.f;
    for (int i = threadIdx.x; i < C; i += 256) {
        ls += sq[i];
        np += pres[i];
    }
    ls = block_reduce_sum_256(ls, sbuf);
    np = block_reduce_sum_256(np, sbuf);
    if (threadIdx.x == 0) out[0] = ls / fmaxf(np, 1.f);
}

extern "C" void kernel_launch(void* const* d_in, const int* in_sizes, int n_in,
                              void* d_out, int out_size, void* d_ws, size_t ws_size,
                              hipStream_t stream) {
    const float* x    = (const float*)d_in[0];
    const int*   l    = (const int*)d_in[1];
    const float* cimg = (const float*)d_in[2];
    const float* cskt = (const float*)d_in[3];

    const int B = in_sizes[1];
    const int D = in_sizes[0] / B;     // 256
    const int C = in_sizes[2] / D;     // 1000

    int* ws_i     = (int*)d_ws;
    int* sums_i   = ws_i;                              // [C*D]
    int* tot      = sums_i + (size_t)C * D;            // [C]   (zeroed with sums)
    int* cnt_i    = tot + C;                           // [C]
    int* cursor   = cnt_i + C;                         // [C*CPAD]
    int* perm     = cursor + (size_t)C * CPAD;         // [B]
    int* lsorted  = perm + B;                          // [B]
    float* sq     = (float*)(lsorted + B);             // [C]
    float* pres   = sq + C;                            // [C]

    // zero sums_i + tot (adjacent) every call (graph replay safe)
    hipMemsetAsync(sums_i, 0, sizeof(int) * ((size_t)C * D + C), stream);

    hist_kernel<<<256, 256, 0, stream>>>(l, tot, B);
    scan_kernel<<<1, 1024, 0, stream>>>(tot, cursor, cnt_i, C);
    build_kernel<<<256, 256, 0, stream>>>(l, cursor, perm, lsorted, B);

    const int rowsPerBlock = 4 * SPAN;                 // 4 waves x 64 rows
    const int dblocks = (B + rowsPerBlock - 1) / rowsPerBlock;
    segsum_kernel<<<dblocks, 256, 0, stream>>>(x, perm, lsorted, sums_i, B, D);

    update_kernel<<<C, 256, 0, stream>>>(sums_i, cnt_i, cimg, cskt, sq, pres, C, D);
    finalize_kernel<<<1, 256, 0, stream>>>(sq, pres, (float*)d_out, C);
}

// Round 6
// 164.564 us; speedup vs baseline: 1.0254x; 1.0254x over previous
//
#include <hip/hip_runtime.h>

#define CMAX    1000
#define DSUB    32            // dims per block slice
#define W64     16            // u64 words per class slice (2 dims each)
#define THREADS 1024
#define NCHUNK  32
#define BIAS    8.0f
#define SCALE   65536.0f      // 2^16 fixed-point scale (biased, non-negative)

// ---------------------------------------------------------------------------
// Kernel 1: segment-sum scatter, LDS-privatized, PACKED u64 fixed point.
// Each element is biased non-negative: enc = round((v+8)*2^16)  (<2^20).
// Two dims pack into one u64 -> ONE ds_add_u64 per 2 dims: halves LDS
// atomic instructions vs u32, and the layout (class stride = 16 u64,
// lane word w = tid&15) spreads every wave-instr uniformly over all 16
// LDS double-banks independent of the (random) class -> conflict floor.
// Per-class per-half sums stay < 2^31 -> no cross-half carry.
// Flush unpacks to u32 global atomics (global totals < 2^31).
// ---------------------------------------------------------------------------
__global__ __launch_bounds__(THREADS) void scatter_kernel(
    const float* __restrict__ x, const int* __restrict__ l,
    unsigned int* __restrict__ sums_u, unsigned int* __restrict__ cnt_u,
    int B, int D, int C, int chunk)
{
    __shared__ unsigned long long lsum[CMAX * W64];   // 128 KB
    __shared__ unsigned int      lcnt[CMAX];          // 4 KB

    for (int i = threadIdx.x; i < CMAX * W64; i += THREADS) lsum[i] = 0ULL;
    for (int i = threadIdx.x; i < CMAX; i += THREADS) lcnt[i] = 0u;
    __syncthreads();

    const bool doCount = (blockIdx.y == 0);
    const int dbase = blockIdx.y * DSUB;
    const int w    = threadIdx.x & 15;       // u64 word within class slice
    const int srel = threadIdx.x >> 4;       // 0..63
    const int STEP = THREADS >> 4;           // 64 samples per block-step
    const int DV2  = D >> 1;                 // row stride in float2
    const int off2 = (dbase >> 1) + w;       // float2 index within row

    const float2* __restrict__ x2 = (const float2*)x;

    const int s0 = blockIdx.x * chunk;
    const int s1 = min(B, s0 + chunk);

    int s = s0 + srel;
    // main loop: 8-wide batches -> 8 loads in flight before the 8 atomics
    for (; s + 7 * STEP < s1; s += 8 * STEP) {
        int    cc[8];
        float2 vv[8];
        #pragma unroll
        for (int k = 0; k < 8; ++k) {
            const int sk = s + k * STEP;
            cc[k] = l[sk];
            vv[k] = x2[(size_t)sk * DV2 + off2];
        }
        #pragma unroll
        for (int k = 0; k < 8; ++k) {
            const unsigned lo = __float2uint_rn((vv[k].x + BIAS) * SCALE);
            const unsigned hi = __float2uint_rn((vv[k].y + BIAS) * SCALE);
            const unsigned long long pk =
                ((unsigned long long)hi << 32) | (unsigned long long)lo;
            atomicAdd(&lsum[cc[k] * W64 + w], pk);
        }
        if (doCount && w == 0) {
            #pragma unroll
            for (int k = 0; k < 8; ++k) atomicAdd(&lcnt[cc[k]], 1u);
        }
    }
    for (; s < s1; s += STEP) {
        const int c = l[s];
        const float2 v = x2[(size_t)s * DV2 + off2];
        const unsigned lo = __float2uint_rn((v.x + BIAS) * SCALE);
        const unsigned hi = __float2uint_rn((v.y + BIAS) * SCALE);
        atomicAdd(&lsum[c * W64 + w],
                  ((unsigned long long)hi << 32) | (unsigned long long)lo);
        if (doCount && w == 0) atomicAdd(&lcnt[c], 1u);
    }
    __syncthreads();

    // flush: unpack u64 halves -> native u32 global atomics
    for (int i = threadIdx.x; i < C * W64; i += THREADS) {
        const unsigned long long val = lsum[i];
        if (val) {
            const int c = i >> 4, ww = i & 15;
            const unsigned lo = (unsigned)(val & 0xffffffffULL);
            const unsigned hi = (unsigned)(val >> 32);
            unsigned* dst = sums_u + (size_t)c * D + dbase + (ww << 1);
            if (lo) atomicAdd(dst, lo);
            if (hi) atomicAdd(dst + 1, hi);
        }
    }
    if (doCount)
        for (int i = threadIdx.x; i < C; i += THREADS) {
            const unsigned v = lcnt[i];
            if (v) atomicAdd(&cnt_u[i], v);
        }
}

// ---------------------------------------------------------------------------
// block-wide sum over 256 threads (4 waves); result broadcast to all threads
// ---------------------------------------------------------------------------
__device__ __forceinline__ float block_reduce_sum_256(float v, float* sbuf) {
    #pragma unroll
    for (int o = 32; o > 0; o >>= 1) v += __shfl_down(v, o, 64);
    __syncthreads();                 // protect sbuf across repeated calls
    if ((threadIdx.x & 63) == 0) sbuf[threadIdx.x >> 6] = v;
    __syncthreads();
    return sbuf[0] + sbuf[1] + sbuf[2] + sbuf[3];
}

// ---------------------------------------------------------------------------
// Kernel 2: per-class momentum update + L2 renorm + squared distance.
// One block (256 threads == D) per class. Un-bias in double for safety.
// ---------------------------------------------------------------------------
__global__ __launch_bounds__(256) void update_kernel(
    const unsigned int* __restrict__ sums_u, const unsigned int* __restrict__ cnt_u,
    const float* __restrict__ cimg, const float* __restrict__ cskt,
    float* __restrict__ sq_out, float* __restrict__ pres_out, int C, int D)
{
    __shared__ float sbuf[4];
    __shared__ float cshare;
    const int c = blockIdx.x;
    const int t = threadIdx.x;

    const unsigned su = sums_u[(size_t)c * D + t];
    if (t == 0) cshare = (float)cnt_u[c];
    __syncthreads();
    const float cnt = cshare;

    // decode: su = sum over class of round((v + 8) * 2^16)
    const double ssum = (double)su * (1.0 / 65536.0) - 8.0 * (double)cnt;
    const bool present = cnt > 0.5f;
    const size_t idx = (size_t)c * D + t;
    const float ci = cimg[idx];
    const float cs = cskt[idx];
    const float mean = (float)(ssum / (double)fmaxf(cnt, 1.f));
    const float upd = ci * 0.9f + mean * 0.1f;
    const float n2 = block_reduce_sum_256(upd * upd, sbuf);
    const float inv = 1.0f / sqrtf(n2);
    const float newv = present ? upd * inv : ci;
    const float df = newv - cs;
    const float sq = block_reduce_sum_256(df * df, sbuf);
    if (t == 0) {
        sq_out[c]   = present ? sq : 0.f;
        pres_out[c] = present ? 1.f : 0.f;
    }
}

// ---------------------------------------------------------------------------
// Kernel 3: final reduction over classes -> scalar loss
// ---------------------------------------------------------------------------
__global__ __launch_bounds__(256) void finalize_kernel(
    const float* __restrict__ sq, const float* __restrict__ pres,
    float* __restrict__ out, int C)
{
    __shared__ float sbuf[4];
    float ls = 0.f, np = 0.f;
    for (int i = threadIdx.x; i < C; i += 256) {
        ls += sq[i];
        np += pres[i];
    }
    ls = block_reduce_sum_256(ls, sbuf);
    np = block_reduce_sum_256(np, sbuf);
    if (threadIdx.x == 0) out[0] = ls / fmaxf(np, 1.f);
}

extern "C" void kernel_launch(void* const* d_in, const int* in_sizes, int n_in,
                              void* d_out, int out_size, void* d_ws, size_t ws_size,
                              hipStream_t stream) {
    const float* x    = (const float*)d_in[0];
    const int*   l    = (const int*)d_in[1];
    const float* cimg = (const float*)d_in[2];
    const float* cskt = (const float*)d_in[3];

    const int B = in_sizes[1];
    const int D = in_sizes[0] / B;     // 256
    const int C = in_sizes[2] / D;     // 1000

    unsigned int* sums_u = (unsigned int*)d_ws;        // [C*D]
    unsigned int* cnt_u  = sums_u + (size_t)C * D;     // [C]
    float* sq            = (float*)(cnt_u + C);        // [C]
    float* pres          = sq + C;                     // [C]

    // zero the accumulators (1 MB) every call (graph replay safe)
    hipMemsetAsync(d_ws, 0, sizeof(unsigned int) * ((size_t)C * D + C), stream);

    const int chunk = (B + NCHUNK - 1) / NCHUNK;
    dim3 grid(NCHUNK, D / DSUB);       // 32 x 8 = 256 blocks (1/CU)

    scatter_kernel<<<grid, THREADS, 0, stream>>>(x, l, sums_u, cnt_u, B, D, C, chunk);
    update_kernel<<<C, 256, 0, stream>>>(sums_u, cnt_u, cimg, cskt, sq, pres, C, D);
    finalize_kernel<<<1, 256, 0, stream>>>(sq, pres, (float*)d_out, C);
}

// Round 7
// 140.110 us; speedup vs baseline: 1.2043x; 1.1745x over previous
//
#include <hip/hip_runtime.h>

#define CMAX    1000
#define FIXS    1048576.0f    // 2^20 fixed-point scale
#define INVFIXS (1.0f / 1048576.0f)
#define NB_HIST 256
#define NB_BLD  128
#define SPAN    64            // sorted rows per wave in segsum

// ---------------------------------------------------------------------------
// Pass A: label histogram (LDS-privatized) -> tot[c]
// ---------------------------------------------------------------------------
__global__ __launch_bounds__(256) void hist_kernel(
    const int* __restrict__ l, int* __restrict__ tot, int B)
{
    __shared__ int h[CMAX];
    for (int i = threadIdx.x; i < CMAX; i += 256) h[i] = 0;
    __syncthreads();
    const int per  = (B + gridDim.x - 1) / gridDim.x;
    const int base = blockIdx.x * per;
    const int end  = min(B, base + per);
    for (int i = base + threadIdx.x; i < end; i += 256)
        atomicAdd(&h[l[i]], 1);
    __syncthreads();
    for (int i = threadIdx.x; i < CMAX; i += 256) {
        const int v = h[i];
        if (v) atomicAdd(&tot[i], v);
    }
}

// ---------------------------------------------------------------------------
// Pass B: exclusive scan of tot -> offs[0..C] (pristine), gcur[c] (working
// reservation cursors), cnt_i[c] = tot[c].
// ---------------------------------------------------------------------------
__global__ __launch_bounds__(1024) void scan_kernel(
    const int* __restrict__ tot, int* __restrict__ offs,
    int* __restrict__ gcur, int* __restrict__ cnt_i, int C, int B)
{
    __shared__ int s[1024];
    const int t = threadIdx.x;
    const int v = (t < C) ? tot[t] : 0;
    s[t] = v;
    if (t < C) cnt_i[t] = v;
    for (int off = 1; off < 1024; off <<= 1) {
        __syncthreads();
        const int u = (t >= off) ? s[t - off] : 0;
        __syncthreads();
        s[t] += u;
    }
    __syncthreads();
    if (t < C) {
        const int e = s[t] - v;       // exclusive prefix
        offs[t] = e;
        gcur[t] = e;
    }
    if (t == 0) offs[C] = B;
}

// ---------------------------------------------------------------------------
// Pass C: two-level permutation build. Per block: LDS histogram of its
// label range, ONE global reservation atomic per present class (~870/block,
// 128-way contention max), then LDS-cursor placement. No hot global address.
// ---------------------------------------------------------------------------
__global__ __launch_bounds__(1024) void build_kernel(
    const int* __restrict__ l, int* __restrict__ gcur,
    int* __restrict__ perm, int B)
{
    __shared__ int lhist[CMAX];
    __shared__ int lbase[CMAX];
    const int per  = (B + gridDim.x - 1) / gridDim.x;
    const int base = blockIdx.x * per;
    const int end  = min(B, base + per);

    for (int i = threadIdx.x; i < CMAX; i += 1024) lhist[i] = 0;
    __syncthreads();
    for (int i = base + threadIdx.x; i < end; i += 1024)
        atomicAdd(&lhist[l[i]], 1);
    __syncthreads();
    for (int c = threadIdx.x; c < CMAX; c += 1024) {
        const int n = lhist[c];
        lbase[c] = n ? atomicAdd(&gcur[c], n) : 0;
        lhist[c] = 0;                 // reuse as local cursor
    }
    __syncthreads();
    for (int i = base + threadIdx.x; i < end; i += 1024) {
        const int c = l[i];
        const int r = atomicAdd(&lhist[c], 1);
        perm[lbase[c] + r] = i;
    }
}

// ---------------------------------------------------------------------------
// Pass D: segment-sum over sorted order. One wave per SPAN=64 sorted rows.
// Each row = ONE contiguous 1KB wave load (lane k -> dims 4k..4k+3).
// Per-lane register fixed-point accumulation; class boundaries from binary
// search on pristine offs[] (runs avg ~B/C = 524 rows, so ~1.1 runs/wave).
// Zero LDS traffic in the hot loop.
// ---------------------------------------------------------------------------
__global__ __launch_bounds__(256) void segsum_kernel(
    const float* __restrict__ x, const int* __restrict__ perm,
    const int* __restrict__ offs, int* __restrict__ sums_i,
    int B, int D, int C)
{
    const int lane = threadIdx.x & 63;
    const int wid  = (int)((blockIdx.x * blockDim.x + threadIdx.x) >> 6);
    const int p0 = wid * SPAN;
    if (p0 >= B) return;
    const int n  = min(SPAN, B - p0);
    const int DV = D >> 2;
    const float4* __restrict__ x4 = (const float4*)x;

    // preload this wave's perm entries (one coalesced load, then shfl-bcast)
    const int myidx = (p0 + lane < B) ? perm[p0 + lane] : 0;

    // binary search: cur = max c with offs[c] <= p0
    int lo = 0, hi = C - 1;
    while (lo < hi) {
        const int mid = (lo + hi + 1) >> 1;
        if (offs[mid] <= p0) lo = mid; else hi = mid - 1;
    }
    int cur = lo;
    int nxt = offs[cur + 1];

    int ax = 0, ay = 0, az = 0, aw = 0;
    float4 vnext = x4[(size_t)__shfl(myidx, 0, 64) * DV + lane];

    for (int it = 0; it < n; ++it) {
        const float4 v = vnext;
        if (it + 1 < n)
            vnext = x4[(size_t)__shfl(myidx, it + 1, 64) * DV + lane];
        const int p = p0 + it;
        while (p >= nxt) {            // wave-uniform; fires ~0.12x per wave
            if (ax | ay | az | aw) {
                int* dst = sums_i + (size_t)cur * D + (lane << 2);
                atomicAdd(dst + 0, ax);
                atomicAdd(dst + 1, ay);
                atomicAdd(dst + 2, az);
                atomicAdd(dst + 3, aw);
                ax = ay = az = aw = 0;
            }
            ++cur;
            nxt = offs[cur + 1];
        }
        ax += __float2int_rn(v.x * FIXS);
        ay += __float2int_rn(v.y * FIXS);
        az += __float2int_rn(v.z * FIXS);
        aw += __float2int_rn(v.w * FIXS);
    }
    int* dst = sums_i + (size_t)cur * D + (lane << 2);
    atomicAdd(dst + 0, ax);
    atomicAdd(dst + 1, ay);
    atomicAdd(dst + 2, az);
    atomicAdd(dst + 3, aw);
}

// ---------------------------------------------------------------------------
// block-wide sum over 256 threads (4 waves); result broadcast to all threads
// ---------------------------------------------------------------------------
__device__ __forceinline__ float block_reduce_sum_256(float v, float* sbuf) {
    #pragma unroll
    for (int o = 32; o > 0; o >>= 1) v += __shfl_down(v, o, 64);
    __syncthreads();                 // protect sbuf across repeated calls
    if ((threadIdx.x & 63) == 0) sbuf[threadIdx.x >> 6] = v;
    __syncthreads();
    return sbuf[0] + sbuf[1] + sbuf[2] + sbuf[3];
}

// ---------------------------------------------------------------------------
// Per-class momentum update + L2 renorm + squared distance.
// One block (256 threads == D) per class.
// ---------------------------------------------------------------------------
__global__ __launch_bounds__(256) void update_kernel(
    const int* __restrict__ sums_i, const int* __restrict__ cnt_i,
    const float* __restrict__ cimg, const float* __restrict__ cskt,
    float* __restrict__ sq_out, float* __restrict__ pres_out, int C, int D)
{
    __shared__ float sbuf[4];
    __shared__ float cshare;
    const int c = blockIdx.x;
    const int t = threadIdx.x;

    const float ssum = (float)sums_i[(size_t)c * D + t] * INVFIXS;
    if (t == 0) cshare = (float)cnt_i[c];
    __syncthreads();
    const float cnt = cshare;

    const bool present = cnt > 0.5f;
    const size_t idx = (size_t)c * D + t;
    const float ci = cimg[idx];
    const float cs = cskt[idx];
    const float mean = ssum / fmaxf(cnt, 1.f);
    const float upd = ci * 0.9f + mean * 0.1f;
    const float n2 = block_reduce_sum_256(upd * upd, sbuf);
    const float inv = 1.0f / sqrtf(n2);
    const float newv = present ? upd * inv : ci;
    const float df = newv - cs;
    const float sq = block_reduce_sum_256(df * df, sbuf);
    if (t == 0) {
        sq_out[c]   = present ? sq : 0.f;
        pres_out[c] = present ? 1.f : 0.f;
    }
}

// ---------------------------------------------------------------------------
// Final reduction over classes -> scalar loss
// ---------------------------------------------------------------------------
__global__ __launch_bounds__(256) void finalize_kernel(
    const float* __restrict__ sq, const float* __restrict__ pres,
    float* __restrict__ out, int C)
{
    __shared__ float sbuf[4];
    float ls = 0.f, np = 0.f;
    for (int i = threadIdx.x; i < C; i += 256) {
        ls += sq[i];
        np += pres[i];
    }
    ls = block_reduce_sum_256(ls, sbuf);
    np = block_reduce_sum_256(np, sbuf);
    if (threadIdx.x == 0) out[0] = ls / fmaxf(np, 1.f);
}

extern "C" void kernel_launch(void* const* d_in, const int* in_sizes, int n_in,
                              void* d_out, int out_size, void* d_ws, size_t ws_size,
                              hipStream_t stream) {
    const float* x    = (const float*)d_in[0];
    const int*   l    = (const int*)d_in[1];
    const float* cimg = (const float*)d_in[2];
    const float* cskt = (const float*)d_in[3];

    const int B = in_sizes[1];
    const int D = in_sizes[0] / B;     // 256
    const int C = in_sizes[2] / D;     // 1000

    int* sums_i = (int*)d_ws;                     // [C*D]
    int* tot    = sums_i + (size_t)C * D;         // [C]   (zeroed with sums)
    int* cnt_i  = tot + C;                        // [C]
    int* offs   = cnt_i + C;                      // [C+1]
    int* gcur   = offs + C + 1;                   // [C]
    int* perm   = gcur + C;                       // [B]
    float* sq   = (float*)(perm + B);             // [C]
    float* pres = sq + C;                         // [C]

    // zero sums_i + tot (adjacent) every call (graph-replay safe)
    hipMemsetAsync(sums_i, 0, sizeof(int) * ((size_t)C * D + C), stream);

    hist_kernel<<<NB_HIST, 256, 0, stream>>>(l, tot, B);
    scan_kernel<<<1, 1024, 0, stream>>>(tot, offs, gcur, cnt_i, C, B);
    build_kernel<<<NB_BLD, 1024, 0, stream>>>(l, gcur, perm, B);

    const int waves   = (B + SPAN - 1) / SPAN;
    const int dblocks = (waves + 3) / 4;          // 4 waves per 256-thr block
    segsum_kernel<<<dblocks, 256, 0, stream>>>(x, perm, offs, sums_i, B, D, C);

    update_kernel<<<C, 256, 0, stream>>>(sums_i, cnt_i, cimg, cskt, sq, pres, C, D);
    finalize_kernel<<<1, 256, 0, stream>>>(sq, pres, (float*)d_out, C);
}